// Round 10
// baseline (290.420 us; speedup 1.0000x reference)
//
#include <hip/hip_runtime.h>
#include <hip/hip_bf16.h>

// Problem: B=16, C=64, H=256, W=256, P=2
// y = haar2d_inv( sum_p softthr( (haar2d(x)*v_p) @ w_p^T, tau_p ) ) + x
//
// ws: bf16 (b,c,wref,h) slab (128 MiB) + bf16 weights + packed/permuted v,tau.
//   k_prep : conv_w->bf16; v,tau -> bf16x2 packed, [w][h_inplace] layout
//   k_fwdW : x(f32) -> Hw(x) via staged register lifting; w-major [256][33]
//            f32 tile. Transposed+permuted store now USHORT8 (16B/lane,
//            wp-major so LDS reads stay <=2-way; round-9's 2B scalar stores
//            = 128B/instr were the latency bottleneck theory).
//   k_mid  : per (b,w) slab: staged-lifting Haar-H fwd -> MFMA mix -> staged
//            inverse -> store. B-fragments hoisted once/thread. (unchanged)
//   k_invW : ushort8 gather -> staged inverse lifting -> +x -> y.

namespace {

constexpr float kNorm = 0.70710678118654752440f;

typedef __attribute__((ext_vector_type(8))) short short8;
typedef __attribute__((ext_vector_type(4))) float f32x4;
typedef __attribute__((ext_vector_type(8))) unsigned short ushort8;
typedef __attribute__((ext_vector_type(4))) unsigned int uint4v;

// in-place lifting position -> reference subband position (n=256, 8 levels)
__device__ __forceinline__ int ip2ref(int p) {
  if (p == 0) return 0;
  const int j = __builtin_ctz(p) + 1;
  return (256 >> j) + (p >> j);
}
// reference subband position -> in-place lifting position
__device__ __forceinline__ int ref2ip(int r) {
  if (r == 0) return 0;
  const int tb = 31 - __builtin_clz(r);
  const int j = 8 - tb;
  return ((r - (1 << tb)) << j) | (1 << (j - 1));
}

__device__ __forceinline__ unsigned short f2bf(float f) {  // f32->bf16 RN
  unsigned int u = __float_as_uint(f);
  u += 0x7FFFu + ((u >> 16) & 1u);
  return (unsigned short)(u >> 16);
}
__device__ __forceinline__ float bf2f(unsigned int u) {
  return __uint_as_float((u & 0xFFFFu) << 16);
}
__device__ __forceinline__ unsigned pk2(float lo, float hi) {
  return (unsigned)f2bf(lo) | ((unsigned)f2bf(hi) << 16);
}

// 3-level forward Haar lifting on 8 values (in-place position convention)
__device__ __forceinline__ void lift3f(const float f[8], float o[8]) {
  const float a0 = kNorm * (f[0] + f[1]), d10 = kNorm * (f[0] - f[1]);
  const float a1 = kNorm * (f[2] + f[3]), d11 = kNorm * (f[2] - f[3]);
  const float a2 = kNorm * (f[4] + f[5]), d12 = kNorm * (f[4] - f[5]);
  const float a3 = kNorm * (f[6] + f[7]), d13 = kNorm * (f[6] - f[7]);
  const float b0 = kNorm * (a0 + a1), d20 = kNorm * (a0 - a1);
  const float b1 = kNorm * (a2 + a3), d21 = kNorm * (a2 - a3);
  o[0] = kNorm * (b0 + b1);
  o[4] = kNorm * (b0 - b1);
  o[2] = d20; o[6] = d21;
  o[1] = d10; o[3] = d11; o[5] = d12; o[7] = d13;
}
// inverse of lift3f
__device__ __forceinline__ void ilift3f(const float f[8], float o[8]) {
  const float b0 = kNorm * (f[0] + f[4]), b1 = kNorm * (f[0] - f[4]);
  const float a0 = kNorm * (b0 + f[2]), a1 = kNorm * (b0 - f[2]);
  const float a2 = kNorm * (b1 + f[6]), a3 = kNorm * (b1 - f[6]);
  o[0] = kNorm * (a0 + f[1]); o[1] = kNorm * (a0 - f[1]);
  o[2] = kNorm * (a1 + f[3]); o[3] = kNorm * (a1 - f[3]);
  o[4] = kNorm * (a2 + f[5]); o[5] = kNorm * (a2 - f[5]);
  o[6] = kNorm * (a3 + f[7]); o[7] = kNorm * (a3 - f[7]);
}

// ---------------- Kernel 0: weights -> bf16; v,tau -> packed/permuted -------
__global__ __launch_bounds__(256) void k_prep(const float* __restrict__ cw,
                                              const float* __restrict__ vv,
                                              const float* __restrict__ tt,
                                              unsigned short* __restrict__ wb,
                                              unsigned int* __restrict__ vpk,
                                              unsigned int* __restrict__ tpk) {
  const int idx = blockIdx.x * 256 + threadIdx.x;  // 65536 = 256 w x 256 hp
  if (idx < 8192) wb[idx] = f2bf(cw[idx]);
  const int w = idx >> 8;
  const int hp = idx & 255;                 // in-place h position
  const int off = (ip2ref(hp) << 8) + w;    // reference coord
  vpk[idx] = pk2(vv[off], vv[65536 + off]);
  tpk[idx] = pk2(tt[off], tt[65536 + off]);
}

// ---------------- Kernel 1: forward Haar along W (staged), bf16 store -------
__global__ __launch_bounds__(256) void k_fwdW(const float* __restrict__ x,
                                              unsigned short* __restrict__ xt) {
  __shared__ float tile[256][33];  // w-major: [w][h], pitch 33
  const int blk = blockIdx.x;      // img*8 + htile
  const int img = blk >> 3;        // b*64 + c
  const int h0 = (blk & 7) << 5;
  const int tid = threadIdx.x;

  const float* __restrict__ src = x + ((size_t)img << 16) + ((size_t)h0 << 8);

  // ---- S1: levels 1-3 in registers (8 consecutive w per task) ----
  const int hR = tid >> 3;  // 0..31
  const int g = tid & 7;    // 0..7
#pragma unroll
  for (int it = 0; it < 4; ++it) {
    const int w0 = (g + (it << 3)) << 3;
    const float4 u = *reinterpret_cast<const float4*>(src + (hR << 8) + w0);
    const float4 v2 = *reinterpret_cast<const float4*>(src + (hR << 8) + w0 + 4);
    float f[8] = {u.x, u.y, u.z, u.w, v2.x, v2.y, v2.z, v2.w};
    float o[8];
    lift3f(f, o);
#pragma unroll
    for (int j = 0; j < 8; ++j) tile[w0 + j][hR] = o[j];
  }
  __syncthreads();

  // ---- S2: levels 4-6 on stride-8 positions ----
  if (tid < 128) {
    const int row = tid & 31;
    const int tq = tid >> 5;  // 0..3
    const int wq = tq << 6;
    float f[8], o[8];
#pragma unroll
    for (int j = 0; j < 8; ++j) f[j] = tile[wq + (j << 3)][row];
    lift3f(f, o);
#pragma unroll
    for (int j = 0; j < 8; ++j) tile[wq + (j << 3)][row] = o[j];
  }
  __syncthreads();

  // ---- S3: levels 7-8 on {0,64,128,192} ----
  if (tid < 32) {
    const float f0 = tile[0][tid], f1 = tile[64][tid];
    const float f2 = tile[128][tid], f3 = tile[192][tid];
    const float a0 = kNorm * (f0 + f1), d0 = kNorm * (f0 - f1);
    const float a1 = kNorm * (f2 + f3), d1 = kNorm * (f2 - f3);
    tile[0][tid] = kNorm * (a0 + a1);
    tile[64][tid] = d0;
    tile[128][tid] = kNorm * (a0 - a1);
    tile[192][tid] = d1;
  }
  __syncthreads();

  // ---- transposed+permuted store, ushort8 (16B/lane), wp-major ----
  // LDS reads <=2-way (wp consecutive across lanes); global scatters 16x64B
  // lines per instr (1KB/instr vs round-9's 128B/instr scalar stores).
  unsigned short* __restrict__ dst = xt + ((size_t)img << 16) + h0;
#pragma unroll
  for (int k = 0; k < 4; ++k) {
    const int idx = (k << 8) + tid;   // 0..1023
    const int wp = idx >> 2;          // in-place w, consecutive across lanes
    const int hseg = (idx & 3) << 3;  // 0,8,16,24
    const int wr = ip2ref(wp);
    ushort8 s;
#pragma unroll
    for (int j = 0; j < 8; ++j) s[j] = f2bf(tile[wp][hseg + j]);
    *reinterpret_cast<ushort8*>(dst + ((size_t)wr << 8) + hseg) = s;
  }
}

// ---------------- Kernel 2: staged Haar-H + MFMA mix (h-major packed LDS) ---
// tile dword (h, cdw): dwidx = h*32 + ((cdw + 4*(h&7) + 8*((h>>3)&3)) & 31)
__device__ __forceinline__ int swzc(int h, int cdw) {
  return (h << 5) | ((cdw + ((h & 7) << 2) + (((h >> 3) & 3) << 3)) & 31);
}

__global__ __launch_bounds__(256, 3) void k_mid(
    unsigned short* __restrict__ ws, const unsigned short* __restrict__ wb,
    const unsigned int* __restrict__ vpk, const unsigned int* __restrict__ tpk) {
  __shared__ unsigned int t32[8192];  // 32 KiB: [h=256][cdw=32] swizzled
  __shared__ unsigned int vt[512];    // [0..255]=v packed, [256..511]=tau packed
  unsigned short* t16 = reinterpret_cast<unsigned short*>(t32);

  const int blk = blockIdx.x;  // b*256 + w
  const int b = blk >> 8;
  const int w = blk & 255;
  const int tid = threadIdx.x;

  unsigned short* __restrict__ base = ws + ((size_t)b << 22) + ((size_t)w << 8);

  // stage v/tau (coalesced; already ip2ref-permuted by k_prep)
  vt[tid] = vpk[(w << 8) + tid];
  vt[256 + tid] = tpk[(w << 8) + tid];

  // ---- B-fragment preload: mt-invariant, load ONCE (64 VGPRs, on purpose).
  const int l15 = tid & 15;
  const int l4 = (tid & 63) >> 4;
  short8 Bf[4][4];
#pragma unroll
  for (int og = 0; og < 4; ++og) {
    const int o = (og << 4) + l15;
    const unsigned short* wr0 = wb + (o << 6) + (l4 << 3);         // p=0
    const unsigned short* wr1 = wb + 4096 + (o << 6) + (l4 << 3);  // p=1
    Bf[og][0] = *reinterpret_cast<const short8*>(wr0);
    Bf[og][1] = *reinterpret_cast<const short8*>(wr0 + 32);
    Bf[og][2] = *reinterpret_cast<const short8*>(wr1);
    Bf[og][3] = *reinterpret_cast<const short8*>(wr1 + 32);
  }

  // ---- S1: global->reg, fwd levels 1-3 in registers, write tile ----
  const int cdw = tid >> 3;  // 0..31 (channel pair)
  const int c0 = cdw << 1;
  const int o8 = tid & 7;
#pragma unroll
  for (int it = 0; it < 4; ++it) {
    const int h0 = (o8 << 3) + (it << 6);
    const ushort8 rA =
        *reinterpret_cast<const ushort8*>(base + ((size_t)c0 << 16) + h0);
    const ushort8 rB =
        *reinterpret_cast<const ushort8*>(base + ((size_t)(c0 + 1) << 16) + h0);
    float fa[8], fb[8], oa[8], ob[8];
#pragma unroll
    for (int j = 0; j < 8; ++j) {
      fa[j] = bf2f(rA[j]);
      fb[j] = bf2f(rB[j]);
    }
    lift3f(fa, oa);
    lift3f(fb, ob);
#pragma unroll
    for (int j = 0; j < 8; ++j) t32[swzc(h0 + j, cdw)] = pk2(oa[j], ob[j]);
  }
  __syncthreads();

  // ---- S2: fwd levels 4-6 (8 values @ stride 8), 128 threads ----
  if (tid < 128) {
    const int cd = tid & 31;
    const int h0 = (tid >> 5) << 6;
    unsigned int g[8];
#pragma unroll
    for (int k = 0; k < 8; ++k) g[k] = t32[swzc(h0 + (k << 3), cd)];
    float fa[8], fb[8], oa[8], ob[8];
#pragma unroll
    for (int k = 0; k < 8; ++k) {
      fa[k] = bf2f(g[k]);
      fb[k] = bf2f(g[k] >> 16);
    }
    lift3f(fa, oa);
    lift3f(fb, ob);
#pragma unroll
    for (int k = 0; k < 8; ++k)
      t32[swzc(h0 + (k << 3), cd)] = pk2(oa[k], ob[k]);
  }
  __syncthreads();

  // ---- S3: fwd levels 7-8 (4 values @ stride 64), 32 threads ----
  if (tid < 32) {
    unsigned int g[4];
#pragma unroll
    for (int k = 0; k < 4; ++k) g[k] = t32[swzc(k << 6, tid)];
    float fa[4], fb[4];
#pragma unroll
    for (int k = 0; k < 4; ++k) {
      fa[k] = bf2f(g[k]);
      fb[k] = bf2f(g[k] >> 16);
    }
    const float aa0 = kNorm * (fa[0] + fa[1]), da0 = kNorm * (fa[0] - fa[1]);
    const float aa1 = kNorm * (fa[2] + fa[3]), da1 = kNorm * (fa[2] - fa[3]);
    const float ab0 = kNorm * (fb[0] + fb[1]), db0 = kNorm * (fb[0] - fb[1]);
    const float ab1 = kNorm * (fb[2] + fb[3]), db1 = kNorm * (fb[2] - fb[3]);
    t32[swzc(0, tid)] = pk2(kNorm * (aa0 + aa1), kNorm * (ab0 + ab1));
    t32[swzc(64, tid)] = pk2(da0, db0);
    t32[swzc(128, tid)] = pk2(kNorm * (aa0 - aa1), kNorm * (ab0 - ab1));
    t32[swzc(192, tid)] = pk2(da1, db1);
  }
  __syncthreads();

  // ---- GEMM + fused epilogue, per-wave 64-row strip ----
  const int strip = (tid >> 6) << 6;
#pragma unroll 1
  for (int mt = 0; mt < 4; ++mt) {
    const int hh = strip + (mt << 4) + l15;
    const short8 a0 =
        *reinterpret_cast<const short8*>(&t32[swzc(hh, l4 << 2)]);
    const short8 a1 =
        *reinterpret_cast<const short8*>(&t32[swzc(hh, 16 + (l4 << 2))]);
    const int hb = strip + (mt << 4) + (l4 << 2);
    const uint4v vq = *reinterpret_cast<const uint4v*>(&vt[hb]);
    const uint4v tq = *reinterpret_cast<const uint4v*>(&vt[256 + hb]);
#pragma unroll
    for (int og = 0; og < 4; ++og) {
      const int o = (og << 4) + l15;
      f32x4 accL = {0.f, 0.f, 0.f, 0.f};
      f32x4 accH = {0.f, 0.f, 0.f, 0.f};
      accL = __builtin_amdgcn_mfma_f32_16x16x32_bf16(a0, Bf[og][0], accL, 0, 0, 0);
      accH = __builtin_amdgcn_mfma_f32_16x16x32_bf16(a0, Bf[og][2], accH, 0, 0, 0);
      accL = __builtin_amdgcn_mfma_f32_16x16x32_bf16(a1, Bf[og][1], accL, 0, 0, 0);
      accH = __builtin_amdgcn_mfma_f32_16x16x32_bf16(a1, Bf[og][3], accH, 0, 0, 0);
#pragma unroll
      for (int r = 0; r < 4; ++r) {
        const float v0 = bf2f(vq[r]), v1 = bf2f(vq[r] >> 16);
        const float t0 = bf2f(tq[r]), t1 = bf2f(tq[r] >> 16);
        const float g0 = accL[r] * v0;
        const float g1 = accH[r] * v1;
        float rr = 0.f;
        const float q0 = fabsf(g0) - t0;
        if (q0 > 0.f) rr += copysignf(q0, g0);
        const float q1 = fabsf(g1) - t1;
        if (q1 > 0.f) rr += copysignf(q1, g1);
        t16[(swzc(hb + r, o >> 1) << 1) | (o & 1)] = f2bf(rr);
      }
    }
  }
  __syncthreads();

  // ---- inverse S3: levels 8,7 ----
  if (tid < 32) {
    unsigned int g[4];
#pragma unroll
    for (int k = 0; k < 4; ++k) g[k] = t32[swzc(k << 6, tid)];
    float fa[4], fb[4];
#pragma unroll
    for (int k = 0; k < 4; ++k) {
      fa[k] = bf2f(g[k]);
      fb[k] = bf2f(g[k] >> 16);
    }
    const float ua0 = kNorm * (fa[0] + fa[2]), ua1 = kNorm * (fa[0] - fa[2]);
    const float ub0 = kNorm * (fb[0] + fb[2]), ub1 = kNorm * (fb[0] - fb[2]);
    t32[swzc(0, tid)] = pk2(kNorm * (ua0 + fa[1]), kNorm * (ub0 + fb[1]));
    t32[swzc(64, tid)] = pk2(kNorm * (ua0 - fa[1]), kNorm * (ub0 - fb[1]));
    t32[swzc(128, tid)] = pk2(kNorm * (ua1 + fa[3]), kNorm * (ub1 + fb[3]));
    t32[swzc(192, tid)] = pk2(kNorm * (ua1 - fa[3]), kNorm * (ub1 - fb[3]));
  }
  __syncthreads();

  // ---- inverse S2: levels 6,5,4 ----
  if (tid < 128) {
    const int cd = tid & 31;
    const int h0 = (tid >> 5) << 6;
    unsigned int g[8];
#pragma unroll
    for (int k = 0; k < 8; ++k) g[k] = t32[swzc(h0 + (k << 3), cd)];
    float fa[8], fb[8], oa[8], ob[8];
#pragma unroll
    for (int k = 0; k < 8; ++k) {
      fa[k] = bf2f(g[k]);
      fb[k] = bf2f(g[k] >> 16);
    }
    ilift3f(fa, oa);
    ilift3f(fb, ob);
#pragma unroll
    for (int k = 0; k < 8; ++k)
      t32[swzc(h0 + (k << 3), cd)] = pk2(oa[k], ob[k]);
  }
  __syncthreads();

  // ---- inverse S1: levels 3,2,1 in registers + global store ----
#pragma unroll
  for (int it = 0; it < 4; ++it) {
    const int h0 = (o8 << 3) + (it << 6);
    unsigned int g[8];
#pragma unroll
    for (int j = 0; j < 8; ++j) g[j] = t32[swzc(h0 + j, cdw)];
    float fa[8], fb[8], oa[8], ob[8];
#pragma unroll
    for (int j = 0; j < 8; ++j) {
      fa[j] = bf2f(g[j]);
      fb[j] = bf2f(g[j] >> 16);
    }
    ilift3f(fa, oa);
    ilift3f(fb, ob);
    ushort8 sA, sB;
#pragma unroll
    for (int j = 0; j < 8; ++j) {
      sA[j] = f2bf(oa[j]);
      sB[j] = f2bf(ob[j]);
    }
    *reinterpret_cast<ushort8*>(base + ((size_t)c0 << 16) + h0) = sA;
    *reinterpret_cast<ushort8*>(base + ((size_t)(c0 + 1) << 16) + h0) = sB;
  }
}

// ---------------- Kernel 3: staged inverse Haar along W + residual add ------
__global__ __launch_bounds__(256) void k_invW(const unsigned short* __restrict__ at,
                                              const float* __restrict__ x,
                                              float* __restrict__ y) {
  __shared__ float tile[256][33];  // w-major: [w (in-place)][h], pitch 33
  const int blk = blockIdx.x;      // img*8 + htile
  const int img = blk >> 3;
  const int h0 = (blk & 7) << 5;
  const int tid = threadIdx.x;

  // ---- gather, ushort8 (16B/lane), wp-major (LDS writes <=2-way) ----
  const unsigned short* __restrict__ basep = at + ((size_t)img << 16) + h0;
#pragma unroll
  for (int k = 0; k < 4; ++k) {
    const int idx = (k << 8) + tid;
    const int wp = idx >> 2;          // in-place w, consecutive across lanes
    const int hseg = (idx & 3) << 3;  // 0,8,16,24
    const int wr = ip2ref(wp);
    const ushort8 rv =
        *reinterpret_cast<const ushort8*>(basep + ((size_t)wr << 8) + hseg);
#pragma unroll
    for (int j = 0; j < 8; ++j) tile[wp][hseg + j] = bf2f(rv[j]);
  }
  __syncthreads();

  // ---- inverse S3: levels 8,7 on {0,64,128,192} ----
  if (tid < 32) {
    const float f0 = tile[0][tid], f1 = tile[64][tid];
    const float f2 = tile[128][tid], f3 = tile[192][tid];
    const float u0 = kNorm * (f0 + f2), u1 = kNorm * (f0 - f2);
    tile[0][tid] = kNorm * (u0 + f1);
    tile[64][tid] = kNorm * (u0 - f1);
    tile[128][tid] = kNorm * (u1 + f3);
    tile[192][tid] = kNorm * (u1 - f3);
  }
  __syncthreads();

  // ---- inverse S2: levels 6,5,4 on stride-8 positions ----
  if (tid < 128) {
    const int row = tid & 31;
    const int tq = tid >> 5;
    const int wq = tq << 6;
    float f[8], o[8];
#pragma unroll
    for (int j = 0; j < 8; ++j) f[j] = tile[wq + (j << 3)][row];
    ilift3f(f, o);
#pragma unroll
    for (int j = 0; j < 8; ++j) tile[wq + (j << 3)][row] = o[j];
  }
  __syncthreads();

  // ---- inverse S1: levels 3,2,1 in registers, fused +x and y store ----
  const int hR = tid >> 3;  // 0..31
  const int g = tid & 7;    // 0..7
  const float* __restrict__ xs = x + ((size_t)img << 16) + ((size_t)h0 << 8);
  float* __restrict__ yd = y + ((size_t)img << 16) + ((size_t)h0 << 8);
#pragma unroll
  for (int it = 0; it < 4; ++it) {
    const int w0 = (g + (it << 3)) << 3;
    float f[8], o[8];
#pragma unroll
    for (int j = 0; j < 8; ++j) f[j] = tile[w0 + j][hR];
    ilift3f(f, o);
    const float4 xu = *reinterpret_cast<const float4*>(xs + (hR << 8) + w0);
    const float4 xv = *reinterpret_cast<const float4*>(xs + (hR << 8) + w0 + 4);
    float4 y0 = {o[0] + xu.x, o[1] + xu.y, o[2] + xu.z, o[3] + xu.w};
    float4 y1 = {o[4] + xv.x, o[5] + xv.y, o[6] + xv.z, o[7] + xv.w};
    *reinterpret_cast<float4*>(yd + (hR << 8) + w0) = y0;
    *reinterpret_cast<float4*>(yd + (hR << 8) + w0 + 4) = y1;
  }
}

}  // namespace

extern "C" void kernel_launch(void* const* d_in, const int* in_sizes, int n_in,
                              void* d_out, int out_size, void* d_ws, size_t ws_size,
                              hipStream_t stream) {
  (void)in_sizes; (void)n_in; (void)out_size; (void)ws_size;
  const float* x  = (const float*)d_in[0];
  const float* vv = (const float*)d_in[1];
  const float* cw = (const float*)d_in[2];
  const float* tt = (const float*)d_in[3];
  float* y = (float*)d_out;
  unsigned short* ws = (unsigned short*)d_ws;      // 128 MiB bf16 slab
  unsigned short* wb = ws + ((size_t)64 << 20);    // bf16 weights (16 KiB)
  unsigned int* vpk = (unsigned int*)(ws + ((size_t)64 << 20) + 16384);
  unsigned int* tpk = vpk + 65536;                 // 256 KiB each

  k_prep<<<256, 256, 0, stream>>>(cw, vv, tt, wb, vpk, tpk);
  k_fwdW<<<8192, 256, 0, stream>>>(x, ws);
  k_mid <<<4096, 256, 0, stream>>>(ws, wb, vpk, tpk);
  k_invW<<<8192, 256, 0, stream>>>(ws, x, y);
}

// Round 11
// 261.642 us; speedup vs baseline: 1.1100x; 1.1100x over previous
//
#include <hip/hip_runtime.h>
#include <hip/hip_bf16.h>

// Problem: B=16, C=64, H=256, W=256, P=2
// y = haar2d_inv( sum_p softthr( (haar2d(x)*v_p) @ w_p^T, tau_p ) ) + x
//
// Residual folded into the wavelet domain (Haar2d is linear+orthonormal):
//   y = invHaar2d(acc) + x = invHaar2d(acc + Haar2d(x))
// so k_mid adds F (already in LDS as the GEMM A-operand source) to the mix
// output before the inverse transform, and k_invW never reads x:
// total HBM traffic 1280 -> 1024 MiB.
//
// ws: bf16 (b,c,wref,h) slab (128 MiB) + bf16 weights + packed/permuted v,tau.
//   k_prep : conv_w->bf16; v,tau -> bf16x2 packed, [w][h_inplace] layout
//   k_fwdW : x(f32) -> Hw(x) via staged register lifting; ushort8 transposed
//            +permuted store.
//   k_mid  : per (b,w) slab: staged-lifting Haar-H fwd -> MFMA mix (+F) ->
//            staged inverse -> store. B-fragments hoisted once/thread.
//   k_invW : ushort8 gather -> staged inverse lifting -> y (no x read).

namespace {

constexpr float kNorm = 0.70710678118654752440f;

typedef __attribute__((ext_vector_type(8))) short short8;
typedef __attribute__((ext_vector_type(4))) float f32x4;
typedef __attribute__((ext_vector_type(8))) unsigned short ushort8;
typedef __attribute__((ext_vector_type(4))) unsigned int uint4v;

// in-place lifting position -> reference subband position (n=256, 8 levels)
__device__ __forceinline__ int ip2ref(int p) {
  if (p == 0) return 0;
  const int j = __builtin_ctz(p) + 1;
  return (256 >> j) + (p >> j);
}
// reference subband position -> in-place lifting position
__device__ __forceinline__ int ref2ip(int r) {
  if (r == 0) return 0;
  const int tb = 31 - __builtin_clz(r);
  const int j = 8 - tb;
  return ((r - (1 << tb)) << j) | (1 << (j - 1));
}

__device__ __forceinline__ unsigned short f2bf(float f) {  // f32->bf16 RN
  unsigned int u = __float_as_uint(f);
  u += 0x7FFFu + ((u >> 16) & 1u);
  return (unsigned short)(u >> 16);
}
__device__ __forceinline__ float bf2f(unsigned int u) {
  return __uint_as_float((u & 0xFFFFu) << 16);
}
__device__ __forceinline__ unsigned pk2(float lo, float hi) {
  return (unsigned)f2bf(lo) | ((unsigned)f2bf(hi) << 16);
}

// 3-level forward Haar lifting on 8 values (in-place position convention)
__device__ __forceinline__ void lift3f(const float f[8], float o[8]) {
  const float a0 = kNorm * (f[0] + f[1]), d10 = kNorm * (f[0] - f[1]);
  const float a1 = kNorm * (f[2] + f[3]), d11 = kNorm * (f[2] - f[3]);
  const float a2 = kNorm * (f[4] + f[5]), d12 = kNorm * (f[4] - f[5]);
  const float a3 = kNorm * (f[6] + f[7]), d13 = kNorm * (f[6] - f[7]);
  const float b0 = kNorm * (a0 + a1), d20 = kNorm * (a0 - a1);
  const float b1 = kNorm * (a2 + a3), d21 = kNorm * (a2 - a3);
  o[0] = kNorm * (b0 + b1);
  o[4] = kNorm * (b0 - b1);
  o[2] = d20; o[6] = d21;
  o[1] = d10; o[3] = d11; o[5] = d12; o[7] = d13;
}
// inverse of lift3f
__device__ __forceinline__ void ilift3f(const float f[8], float o[8]) {
  const float b0 = kNorm * (f[0] + f[4]), b1 = kNorm * (f[0] - f[4]);
  const float a0 = kNorm * (b0 + f[2]), a1 = kNorm * (b0 - f[2]);
  const float a2 = kNorm * (b1 + f[6]), a3 = kNorm * (b1 - f[6]);
  o[0] = kNorm * (a0 + f[1]); o[1] = kNorm * (a0 - f[1]);
  o[2] = kNorm * (a1 + f[3]); o[3] = kNorm * (a1 - f[3]);
  o[4] = kNorm * (a2 + f[5]); o[5] = kNorm * (a2 - f[5]);
  o[6] = kNorm * (a3 + f[7]); o[7] = kNorm * (a3 - f[7]);
}

// ---------------- Kernel 0: weights -> bf16; v,tau -> packed/permuted -------
__global__ __launch_bounds__(256) void k_prep(const float* __restrict__ cw,
                                              const float* __restrict__ vv,
                                              const float* __restrict__ tt,
                                              unsigned short* __restrict__ wb,
                                              unsigned int* __restrict__ vpk,
                                              unsigned int* __restrict__ tpk) {
  const int idx = blockIdx.x * 256 + threadIdx.x;  // 65536 = 256 w x 256 hp
  if (idx < 8192) wb[idx] = f2bf(cw[idx]);
  const int w = idx >> 8;
  const int hp = idx & 255;                 // in-place h position
  const int off = (ip2ref(hp) << 8) + w;    // reference coord
  vpk[idx] = pk2(vv[off], vv[65536 + off]);
  tpk[idx] = pk2(tt[off], tt[65536 + off]);
}

// ---------------- Kernel 1: forward Haar along W (staged), bf16 store -------
__global__ __launch_bounds__(256) void k_fwdW(const float* __restrict__ x,
                                              unsigned short* __restrict__ xt) {
  __shared__ float tile[256][33];  // w-major: [w][h], pitch 33
  const int blk = blockIdx.x;      // img*8 + htile
  const int img = blk >> 3;        // b*64 + c
  const int h0 = (blk & 7) << 5;
  const int tid = threadIdx.x;

  const float* __restrict__ src = x + ((size_t)img << 16) + ((size_t)h0 << 8);

  // ---- S1: levels 1-3 in registers (8 consecutive w per task) ----
  const int hR = tid >> 3;  // 0..31
  const int g = tid & 7;    // 0..7
#pragma unroll
  for (int it = 0; it < 4; ++it) {
    const int w0 = (g + (it << 3)) << 3;
    const float4 u = *reinterpret_cast<const float4*>(src + (hR << 8) + w0);
    const float4 v2 = *reinterpret_cast<const float4*>(src + (hR << 8) + w0 + 4);
    float f[8] = {u.x, u.y, u.z, u.w, v2.x, v2.y, v2.z, v2.w};
    float o[8];
    lift3f(f, o);
#pragma unroll
    for (int j = 0; j < 8; ++j) tile[w0 + j][hR] = o[j];
  }
  __syncthreads();

  // ---- S2: levels 4-6 on stride-8 positions ----
  if (tid < 128) {
    const int row = tid & 31;
    const int tq = tid >> 5;  // 0..3
    const int wq = tq << 6;
    float f[8], o[8];
#pragma unroll
    for (int j = 0; j < 8; ++j) f[j] = tile[wq + (j << 3)][row];
    lift3f(f, o);
#pragma unroll
    for (int j = 0; j < 8; ++j) tile[wq + (j << 3)][row] = o[j];
  }
  __syncthreads();

  // ---- S3: levels 7-8 on {0,64,128,192} ----
  if (tid < 32) {
    const float f0 = tile[0][tid], f1 = tile[64][tid];
    const float f2 = tile[128][tid], f3 = tile[192][tid];
    const float a0 = kNorm * (f0 + f1), d0 = kNorm * (f0 - f1);
    const float a1 = kNorm * (f2 + f3), d1 = kNorm * (f2 - f3);
    tile[0][tid] = kNorm * (a0 + a1);
    tile[64][tid] = d0;
    tile[128][tid] = kNorm * (a0 - a1);
    tile[192][tid] = d1;
  }
  __syncthreads();

  // ---- transposed+permuted store, ushort8 (16B/lane), wp-major ----
  unsigned short* __restrict__ dst = xt + ((size_t)img << 16) + h0;
#pragma unroll
  for (int k = 0; k < 4; ++k) {
    const int idx = (k << 8) + tid;   // 0..1023
    const int wp = idx >> 2;          // in-place w, consecutive across lanes
    const int hseg = (idx & 3) << 3;  // 0,8,16,24
    const int wr = ip2ref(wp);
    ushort8 s;
#pragma unroll
    for (int j = 0; j < 8; ++j) s[j] = f2bf(tile[wp][hseg + j]);
    *reinterpret_cast<ushort8*>(dst + ((size_t)wr << 8) + hseg) = s;
  }
}

// ---------------- Kernel 2: staged Haar-H + MFMA mix (h-major packed LDS) ---
// tile dword (h, cdw): dwidx = h*32 + ((cdw + 4*(h&7) + 8*((h>>3)&3)) & 31)
__device__ __forceinline__ int swzc(int h, int cdw) {
  return (h << 5) | ((cdw + ((h & 7) << 2) + (((h >> 3) & 3) << 3)) & 31);
}

__global__ __launch_bounds__(256, 3) void k_mid(
    unsigned short* __restrict__ ws, const unsigned short* __restrict__ wb,
    const unsigned int* __restrict__ vpk, const unsigned int* __restrict__ tpk) {
  __shared__ unsigned int t32[8192];  // 32 KiB: [h=256][cdw=32] swizzled
  __shared__ unsigned int vt[512];    // [0..255]=v packed, [256..511]=tau packed
  unsigned short* t16 = reinterpret_cast<unsigned short*>(t32);

  const int blk = blockIdx.x;  // b*256 + w
  const int b = blk >> 8;
  const int w = blk & 255;
  const int tid = threadIdx.x;

  unsigned short* __restrict__ base = ws + ((size_t)b << 22) + ((size_t)w << 8);

  // stage v/tau (coalesced; already ip2ref-permuted by k_prep)
  vt[tid] = vpk[(w << 8) + tid];
  vt[256 + tid] = tpk[(w << 8) + tid];

  // ---- B-fragment preload: mt-invariant, load ONCE (64 VGPRs, on purpose).
  const int l15 = tid & 15;
  const int l4 = (tid & 63) >> 4;
  short8 Bf[4][4];
#pragma unroll
  for (int og = 0; og < 4; ++og) {
    const int o = (og << 4) + l15;
    const unsigned short* wr0 = wb + (o << 6) + (l4 << 3);         // p=0
    const unsigned short* wr1 = wb + 4096 + (o << 6) + (l4 << 3);  // p=1
    Bf[og][0] = *reinterpret_cast<const short8*>(wr0);
    Bf[og][1] = *reinterpret_cast<const short8*>(wr0 + 32);
    Bf[og][2] = *reinterpret_cast<const short8*>(wr1);
    Bf[og][3] = *reinterpret_cast<const short8*>(wr1 + 32);
  }

  // ---- S1: global->reg, fwd levels 1-3 in registers, write tile ----
  const int cdw = tid >> 3;  // 0..31 (channel pair)
  const int c0 = cdw << 1;
  const int o8 = tid & 7;
#pragma unroll
  for (int it = 0; it < 4; ++it) {
    const int h0 = (o8 << 3) + (it << 6);
    const ushort8 rA =
        *reinterpret_cast<const ushort8*>(base + ((size_t)c0 << 16) + h0);
    const ushort8 rB =
        *reinterpret_cast<const ushort8*>(base + ((size_t)(c0 + 1) << 16) + h0);
    float fa[8], fb[8], oa[8], ob[8];
#pragma unroll
    for (int j = 0; j < 8; ++j) {
      fa[j] = bf2f(rA[j]);
      fb[j] = bf2f(rB[j]);
    }
    lift3f(fa, oa);
    lift3f(fb, ob);
#pragma unroll
    for (int j = 0; j < 8; ++j) t32[swzc(h0 + j, cdw)] = pk2(oa[j], ob[j]);
  }
  __syncthreads();

  // ---- S2: fwd levels 4-6 (8 values @ stride 8), 128 threads ----
  if (tid < 128) {
    const int cd = tid & 31;
    const int h0 = (tid >> 5) << 6;
    unsigned int g[8];
#pragma unroll
    for (int k = 0; k < 8; ++k) g[k] = t32[swzc(h0 + (k << 3), cd)];
    float fa[8], fb[8], oa[8], ob[8];
#pragma unroll
    for (int k = 0; k < 8; ++k) {
      fa[k] = bf2f(g[k]);
      fb[k] = bf2f(g[k] >> 16);
    }
    lift3f(fa, oa);
    lift3f(fb, ob);
#pragma unroll
    for (int k = 0; k < 8; ++k)
      t32[swzc(h0 + (k << 3), cd)] = pk2(oa[k], ob[k]);
  }
  __syncthreads();

  // ---- S3: fwd levels 7-8 (4 values @ stride 64), 32 threads ----
  if (tid < 32) {
    unsigned int g[4];
#pragma unroll
    for (int k = 0; k < 4; ++k) g[k] = t32[swzc(k << 6, tid)];
    float fa[4], fb[4];
#pragma unroll
    for (int k = 0; k < 4; ++k) {
      fa[k] = bf2f(g[k]);
      fb[k] = bf2f(g[k] >> 16);
    }
    const float aa0 = kNorm * (fa[0] + fa[1]), da0 = kNorm * (fa[0] - fa[1]);
    const float aa1 = kNorm * (fa[2] + fa[3]), da1 = kNorm * (fa[2] - fa[3]);
    const float ab0 = kNorm * (fb[0] + fb[1]), db0 = kNorm * (fb[0] - fb[1]);
    const float ab1 = kNorm * (fb[2] + fb[3]), db1 = kNorm * (fb[2] - fb[3]);
    t32[swzc(0, tid)] = pk2(kNorm * (aa0 + aa1), kNorm * (ab0 + ab1));
    t32[swzc(64, tid)] = pk2(da0, db0);
    t32[swzc(128, tid)] = pk2(kNorm * (aa0 - aa1), kNorm * (ab0 - ab1));
    t32[swzc(192, tid)] = pk2(da1, db1);
  }
  __syncthreads();

  // ---- GEMM + fused epilogue (acc + F residual), per-wave 64-row strip ----
  // Residual: y = invHaar2d(acc + Haar2d(x)), so write rr + F at each (h,o).
  // F is read from the exact LDS location overwritten by the same lane.
  const int strip = (tid >> 6) << 6;
#pragma unroll 1
  for (int mt = 0; mt < 4; ++mt) {
    const int hh = strip + (mt << 4) + l15;
    const short8 a0 =
        *reinterpret_cast<const short8*>(&t32[swzc(hh, l4 << 2)]);
    const short8 a1 =
        *reinterpret_cast<const short8*>(&t32[swzc(hh, 16 + (l4 << 2))]);
    const int hb = strip + (mt << 4) + (l4 << 2);
    const uint4v vq = *reinterpret_cast<const uint4v*>(&vt[hb]);
    const uint4v tq = *reinterpret_cast<const uint4v*>(&vt[256 + hb]);
#pragma unroll
    for (int og = 0; og < 4; ++og) {
      const int o = (og << 4) + l15;
      f32x4 accL = {0.f, 0.f, 0.f, 0.f};
      f32x4 accH = {0.f, 0.f, 0.f, 0.f};
      accL = __builtin_amdgcn_mfma_f32_16x16x32_bf16(a0, Bf[og][0], accL, 0, 0, 0);
      accH = __builtin_amdgcn_mfma_f32_16x16x32_bf16(a0, Bf[og][2], accH, 0, 0, 0);
      accL = __builtin_amdgcn_mfma_f32_16x16x32_bf16(a1, Bf[og][1], accL, 0, 0, 0);
      accH = __builtin_amdgcn_mfma_f32_16x16x32_bf16(a1, Bf[og][3], accH, 0, 0, 0);
#pragma unroll
      for (int r = 0; r < 4; ++r) {
        const float v0 = bf2f(vq[r]), v1 = bf2f(vq[r] >> 16);
        const float t0 = bf2f(tq[r]), t1 = bf2f(tq[r] >> 16);
        const float g0 = accL[r] * v0;
        const float g1 = accH[r] * v1;
        float rr = 0.f;
        const float q0 = fabsf(g0) - t0;
        if (q0 > 0.f) rr += copysignf(q0, g0);
        const float q1 = fabsf(g1) - t1;
        if (q1 > 0.f) rr += copysignf(q1, g1);
        const int idx16 = (swzc(hb + r, o >> 1) << 1) | (o & 1);
        const float Fv = bf2f(t16[idx16]);  // residual in wavelet domain
        t16[idx16] = f2bf(rr + Fv);
      }
    }
  }
  __syncthreads();

  // ---- inverse S3: levels 8,7 ----
  if (tid < 32) {
    unsigned int g[4];
#pragma unroll
    for (int k = 0; k < 4; ++k) g[k] = t32[swzc(k << 6, tid)];
    float fa[4], fb[4];
#pragma unroll
    for (int k = 0; k < 4; ++k) {
      fa[k] = bf2f(g[k]);
      fb[k] = bf2f(g[k] >> 16);
    }
    const float ua0 = kNorm * (fa[0] + fa[2]), ua1 = kNorm * (fa[0] - fa[2]);
    const float ub0 = kNorm * (fb[0] + fb[2]), ub1 = kNorm * (fb[0] - fb[2]);
    t32[swzc(0, tid)] = pk2(kNorm * (ua0 + fa[1]), kNorm * (ub0 + fb[1]));
    t32[swzc(64, tid)] = pk2(kNorm * (ua0 - fa[1]), kNorm * (ub0 - fb[1]));
    t32[swzc(128, tid)] = pk2(kNorm * (ua1 + fa[3]), kNorm * (ub1 + fb[3]));
    t32[swzc(192, tid)] = pk2(kNorm * (ua1 - fa[3]), kNorm * (ub1 - fb[3]));
  }
  __syncthreads();

  // ---- inverse S2: levels 6,5,4 ----
  if (tid < 128) {
    const int cd = tid & 31;
    const int h0 = (tid >> 5) << 6;
    unsigned int g[8];
#pragma unroll
    for (int k = 0; k < 8; ++k) g[k] = t32[swzc(h0 + (k << 3), cd)];
    float fa[8], fb[8], oa[8], ob[8];
#pragma unroll
    for (int k = 0; k < 8; ++k) {
      fa[k] = bf2f(g[k]);
      fb[k] = bf2f(g[k] >> 16);
    }
    ilift3f(fa, oa);
    ilift3f(fb, ob);
#pragma unroll
    for (int k = 0; k < 8; ++k)
      t32[swzc(h0 + (k << 3), cd)] = pk2(oa[k], ob[k]);
  }
  __syncthreads();

  // ---- inverse S1: levels 3,2,1 in registers + global store ----
#pragma unroll
  for (int it = 0; it < 4; ++it) {
    const int h0 = (o8 << 3) + (it << 6);
    unsigned int g[8];
#pragma unroll
    for (int j = 0; j < 8; ++j) g[j] = t32[swzc(h0 + j, cdw)];
    float fa[8], fb[8], oa[8], ob[8];
#pragma unroll
    for (int j = 0; j < 8; ++j) {
      fa[j] = bf2f(g[j]);
      fb[j] = bf2f(g[j] >> 16);
    }
    ilift3f(fa, oa);
    ilift3f(fb, ob);
    ushort8 sA, sB;
#pragma unroll
    for (int j = 0; j < 8; ++j) {
      sA[j] = f2bf(oa[j]);
      sB[j] = f2bf(ob[j]);
    }
    *reinterpret_cast<ushort8*>(base + ((size_t)c0 << 16) + h0) = sA;
    *reinterpret_cast<ushort8*>(base + ((size_t)(c0 + 1) << 16) + h0) = sB;
  }
}

// ---------------- Kernel 3: staged inverse Haar along W -> y ----------------
__global__ __launch_bounds__(256) void k_invW(const unsigned short* __restrict__ at,
                                              float* __restrict__ y) {
  __shared__ float tile[256][33];  // w-major: [w (in-place)][h], pitch 33
  const int blk = blockIdx.x;      // img*8 + htile
  const int img = blk >> 3;
  const int h0 = (blk & 7) << 5;
  const int tid = threadIdx.x;

  // ---- gather, ushort8 (16B/lane), wp-major (LDS writes <=2-way) ----
  const unsigned short* __restrict__ basep = at + ((size_t)img << 16) + h0;
#pragma unroll
  for (int k = 0; k < 4; ++k) {
    const int idx = (k << 8) + tid;
    const int wp = idx >> 2;          // in-place w, consecutive across lanes
    const int hseg = (idx & 3) << 3;  // 0,8,16,24
    const int wr = ip2ref(wp);
    const ushort8 rv =
        *reinterpret_cast<const ushort8*>(basep + ((size_t)wr << 8) + hseg);
#pragma unroll
    for (int j = 0; j < 8; ++j) tile[wp][hseg + j] = bf2f(rv[j]);
  }
  __syncthreads();

  // ---- inverse S3: levels 8,7 on {0,64,128,192} ----
  if (tid < 32) {
    const float f0 = tile[0][tid], f1 = tile[64][tid];
    const float f2 = tile[128][tid], f3 = tile[192][tid];
    const float u0 = kNorm * (f0 + f2), u1 = kNorm * (f0 - f2);
    tile[0][tid] = kNorm * (u0 + f1);
    tile[64][tid] = kNorm * (u0 - f1);
    tile[128][tid] = kNorm * (u1 + f3);
    tile[192][tid] = kNorm * (u1 - f3);
  }
  __syncthreads();

  // ---- inverse S2: levels 6,5,4 on stride-8 positions ----
  if (tid < 128) {
    const int row = tid & 31;
    const int tq = tid >> 5;
    const int wq = tq << 6;
    float f[8], o[8];
#pragma unroll
    for (int j = 0; j < 8; ++j) f[j] = tile[wq + (j << 3)][row];
    ilift3f(f, o);
#pragma unroll
    for (int j = 0; j < 8; ++j) tile[wq + (j << 3)][row] = o[j];
  }
  __syncthreads();

  // ---- inverse S1: levels 3,2,1 in registers, y store (residual already
  //      folded in wavelet domain by k_mid) ----
  const int hR = tid >> 3;  // 0..31
  const int g = tid & 7;    // 0..7
  float* __restrict__ yd = y + ((size_t)img << 16) + ((size_t)h0 << 8);
#pragma unroll
  for (int it = 0; it < 4; ++it) {
    const int w0 = (g + (it << 3)) << 3;
    float f[8], o[8];
#pragma unroll
    for (int j = 0; j < 8; ++j) f[j] = tile[w0 + j][hR];
    ilift3f(f, o);
    float4 y0 = {o[0], o[1], o[2], o[3]};
    float4 y1 = {o[4], o[5], o[6], o[7]};
    *reinterpret_cast<float4*>(yd + (hR << 8) + w0) = y0;
    *reinterpret_cast<float4*>(yd + (hR << 8) + w0 + 4) = y1;
  }
}

}  // namespace

extern "C" void kernel_launch(void* const* d_in, const int* in_sizes, int n_in,
                              void* d_out, int out_size, void* d_ws, size_t ws_size,
                              hipStream_t stream) {
  (void)in_sizes; (void)n_in; (void)out_size; (void)ws_size;
  const float* x  = (const float*)d_in[0];
  const float* vv = (const float*)d_in[1];
  const float* cw = (const float*)d_in[2];
  const float* tt = (const float*)d_in[3];
  float* y = (float*)d_out;
  unsigned short* ws = (unsigned short*)d_ws;      // 128 MiB bf16 slab
  unsigned short* wb = ws + ((size_t)64 << 20);    // bf16 weights (16 KiB)
  unsigned int* vpk = (unsigned int*)(ws + ((size_t)64 << 20) + 16384);
  unsigned int* tpk = vpk + 65536;                 // 256 KiB each

  k_prep<<<256, 256, 0, stream>>>(cw, vv, tt, wb, vpk, tpk);
  k_fwdW<<<8192, 256, 0, stream>>>(x, ws);
  k_mid <<<4096, 256, 0, stream>>>(ws, wb, vpk, tpk);
  k_invW<<<8192, 256, 0, stream>>>(ws, y);
}